// Round 9
// baseline (290.487 us; speedup 1.0000x reference)
//
#include <hip/hip_runtime.h>

// NonLocalBlock: B=2, C=256, N=D*H*W=6272, mid=128.
// R9 = R8 with single-barrier attn (K AND V double-buffered) + setprio:
//  - LDS 69632 B: Ks0|Ks1 [64][136] + Vt0|Vt1 [128][68] (gfx950 allows
//    >64KB/WG; 2 blocks/CU — same 1.53 avg occupancy as R8's 52KB).
//  - iter kt reads K[kt],V[kt] staged during kt-1; prefetches K/V[kt+1] to
//    regs (issue-early), writes them to the other buffers after softmax;
//    ONE barrier at iter end. PV never waits on this-iter staging.
//    Hazard: buffer reads (iter k) vs its next writes (iter k+1) separated
//    by exactly that barrier. (R8 had 2 barriers + PV gated on mid-iter V.)
//  - T5 s_setprio(1) around QK and PV MFMA chains (independent blocks =
//    m191-positive regime).
//  - proj (MFMA split-x), comb, epi (MFMA) byte-identical to R8.
// ws: Qg f16 | Kg f16 | VtG f16 | attnW f16 | MLg f32 = 13.25 MB.

#define BB  2
#define CC  256
#define NN  6272
#define MID 128
#define KS  4
#define QB  128
#define NT  (NN / 64)
#define LOG2E 1.4426950408889634f

typedef _Float16 half2_t __attribute__((ext_vector_type(2)));
typedef _Float16 half4_t __attribute__((ext_vector_type(4)));
typedef _Float16 half8_t __attribute__((ext_vector_type(8)));
typedef float    floatx16 __attribute__((ext_vector_type(16)));
typedef int      i32x2 __attribute__((ext_vector_type(2)));
typedef unsigned u32x4 __attribute__((ext_vector_type(4)));

__device__ __forceinline__ unsigned pkrtz(float a, float b) {
    return __builtin_bit_cast(unsigned, __builtin_amdgcn_cvt_pkrtz(a, b));
}
__device__ __forceinline__ half8_t cvt8(const float* p) {
    float4 f0 = *(const float4*)p;
    float4 f1 = *(const float4*)(p + 4);
    u32x4 u;
    u[0] = pkrtz(f0.x, f0.y); u[1] = pkrtz(f0.z, f0.w);
    u[2] = pkrtz(f1.x, f1.y); u[3] = pkrtz(f1.z, f1.w);
    return __builtin_bit_cast(half8_t, u);
}

// ---------------------------------------------------------------------------
// Projection (f16 MFMA, split-x) — UNCHANGED from R8.
// ---------------------------------------------------------------------------
__global__ __launch_bounds__(256, 2) void proj_kernel(
    const float* __restrict__ x,
    const float* __restrict__ w1, const float* __restrict__ bi1,
    const float* __restrict__ w2, const float* __restrict__ bi2,
    const float* __restrict__ w3, const float* __restrict__ bi3,
    _Float16* __restrict__ Qg, _Float16* __restrict__ Kg, _Float16* __restrict__ VtG)
{
    const int t    = threadIdx.x;
    const int lane = t & 63;
    const int wave = t >> 6;
    const int l31  = lane & 31;
    const int l5   = lane >> 5;
    const int n0   = blockIdx.x * 64;
    const int b    = blockIdx.y;

    __shared__ _Float16 xhi[64 * 140];
    __shared__ _Float16 xlo[64 * 140];

    floatx16 acc[6];
    #pragma unroll
    for (int i = 0; i < 6; ++i)
        #pragma unroll
        for (int j = 0; j < 16; ++j) acc[i][j] = 0.f;

    for (int phase = 0; phase < 2; ++phase) {
        const int cb = phase * 128;
        if (phase) __syncthreads();
        for (int it = 0; it < 8; ++it) {
            int r = it * 256 + t;
            int c = r >> 4, j4 = (r & 15) << 2;
            float4 v = *(const float4*)(x + ((size_t)b * CC + cb + c) * NN + n0 + j4);
            float vv[4] = {v.x, v.y, v.z, v.w};
            #pragma unroll
            for (int i = 0; i < 4; ++i) {
                _Float16 h = (_Float16)vv[i];
                xhi[(j4 + i) * 140 + c] = h;
                xlo[(j4 + i) * 140 + c] = (_Float16)(vv[i] - (float)h);
            }
        }
        __syncthreads();

        #pragma unroll
        for (int i = 0; i < 6; ++i) {
            const int tau = wave * 6 + i;
            const int pj = tau >> 3, mt = (tau >> 1) & 3, nt = tau & 1;
            const float* w = (pj == 0) ? w1 : (pj == 1) ? w2 : w3;
            const float* wrow = w + (size_t)(mt * 32 + l31) * CC + cb + l5 * 8;
            const _Float16* xr_hi = xhi + (nt * 32 + l31) * 140 + l5 * 8;
            const _Float16* xr_lo = xlo + (nt * 32 + l31) * 140 + l5 * 8;
            #pragma unroll
            for (int ds = 0; ds < 8; ++ds) {
                half8_t wf = cvt8(wrow + ds * 16);
                half8_t ah = *(const half8_t*)(xr_hi + ds * 16);
                half8_t al = *(const half8_t*)(xr_lo + ds * 16);
                if (pj < 2) {
                    acc[i] = __builtin_amdgcn_mfma_f32_32x32x16_f16(ah, wf, acc[i], 0, 0, 0);
                    acc[i] = __builtin_amdgcn_mfma_f32_32x32x16_f16(al, wf, acc[i], 0, 0, 0);
                } else {
                    acc[i] = __builtin_amdgcn_mfma_f32_32x32x16_f16(wf, ah, acc[i], 0, 0, 0);
                    acc[i] = __builtin_amdgcn_mfma_f32_32x32x16_f16(wf, al, acc[i], 0, 0, 0);
                }
            }
        }
    }

    #pragma unroll
    for (int i = 0; i < 6; ++i) {
        const int tau = wave * 6 + i;
        const int pj = tau >> 3, mt = (tau >> 1) & 3, nt = tau & 1;
        if (pj < 2) {
            const float bm = ((pj == 0) ? bi1 : bi2)[mt * 32 + l31];
            const float sc = (pj == 0) ? LOG2E : 1.0f;
            _Float16* eo = ((pj == 0) ? Qg : Kg) + (size_t)b * NN * MID;
            #pragma unroll
            for (int j = 0; j < 16; ++j) {
                int n = n0 + nt * 32 + (j & 3) + 8 * (j >> 2) + 4 * l5;
                eo[(size_t)n * MID + mt * 32 + l31] = (_Float16)((acc[i][j] + bm) * sc);
            }
        } else {
            _Float16* eo = VtG + (size_t)b * MID * NN;
            #pragma unroll
            for (int j = 0; j < 16; ++j) {
                int m = mt * 32 + (j & 3) + 8 * (j >> 2) + 4 * l5;
                eo[(size_t)m * NN + n0 + nt * 32 + l31] = (_Float16)(acc[i][j] + bi3[m]);
            }
        }
    }
}

// ---------------------------------------------------------------------------
// Flash attention partial: q-split 4-wave, KS=4, in-reg P, K+V double-buffer,
// SINGLE barrier per iter. grid (NN/QB, KS, BB), block 256 (4 waves).
// LDS (69632 B): Ks0 | Ks1 [64][136] | Vt0 | Vt1 [128][68].
// Osh [128][136] h aliases Ks0+Ks1 for the store transpose.
// ---------------------------------------------------------------------------
__global__ __launch_bounds__(256, 2) void attn_kernel(
    const _Float16* __restrict__ Qg, const _Float16* __restrict__ Kg,
    const _Float16* __restrict__ VtG, _Float16* __restrict__ Opart,
    float* __restrict__ MLg)
{
    const int t    = threadIdx.x;
    const int lane = t & 63;
    const int wave = t >> 6;        // q-strip owner (0..3)
    const int l31  = lane & 31;
    const int l5   = lane >> 5;
    const int q0   = blockIdx.x * QB;
    const int sp   = blockIdx.y;
    const int b    = blockIdx.z;
    const int kt0  = (NT * sp) / KS;
    const int kt1  = (NT * (sp + 1)) / KS;

    __shared__ __align__(16) char lds[69632];
    _Float16* Ks0 = (_Float16*)lds;               // 64*136 halfs
    _Float16* Ks1 = (_Float16*)(lds + 17408);
    _Float16* Vt0 = (_Float16*)(lds + 34816);     // 128*68 halfs
    _Float16* Vt1 = (_Float16*)(lds + 52224);
    _Float16* Osh = (_Float16*)lds;               // [128][136] alias (Ks0+Ks1)

    const _Float16* Qb = Qg + ((size_t)b * NN + q0 + wave * 32) * MID;
    const _Float16* Kb = Kg + (size_t)b * NN * MID;
    const _Float16* Vb = VtG + (size_t)b * MID * NN;

    half8_t qf[8];
    #pragma unroll
    for (int ds = 0; ds < 8; ++ds)
        qf[ds] = *(const half8_t*)(Qb + (size_t)l31 * MID + ds * 16 + l5 * 8);

    floatx16 o[4];
    #pragma unroll
    for (int dt = 0; dt < 4; ++dt)
        #pragma unroll
        for (int j = 0; j < 16; ++j) o[dt][j] = 0.f;
    float m_run = -3.0e38f, l_run = 0.f;   // m in log2 domain

    const int krow_t = t >> 4, koff_t = (t & 15) * 8;
    const int vd_t   = t >> 3, voff_t = (t & 7) * 8;

    // ---- prologue: stage K[kt0] -> Ks0, V[kt0] -> Vt0 ----
    #pragma unroll
    for (int it = 0; it < 4; ++it) {
        int r = it * 16 + krow_t;
        *(half8_t*)(Ks0 + r * 136 + koff_t) =
            *(const half8_t*)(Kb + (size_t)(kt0 * 64 + r) * MID + koff_t);
    }
    #pragma unroll
    for (int it = 0; it < 4; ++it) {
        int d = it * 32 + vd_t;
        *(half8_t*)(Vt0 + d * 68 + voff_t) =
            *(const half8_t*)(Vb + (size_t)d * NN + kt0 * 64 + voff_t);
    }
    __syncthreads();

    for (int kt = kt0, cbuf = 0; kt < kt1; ++kt, cbuf ^= 1) {
        const int nk = kt * 64;
        _Float16* KBcur = cbuf ? Ks1 : Ks0;
        _Float16* KBnxt = cbuf ? Ks0 : Ks1;
        _Float16* VBcur = cbuf ? Vt1 : Vt0;
        _Float16* VBnxt = cbuf ? Vt0 : Vt1;

        // ---- issue K[kt+1], V[kt+1] global loads -> regs (EARLY) ----
        const int nk2 = (kt + 1 < kt1) ? nk + 64 : nk;   // tail: harmless reload
        half8_t vreg[4], kreg[4];
        #pragma unroll
        for (int it = 0; it < 4; ++it)
            vreg[it] = *(const half8_t*)(Vb + (size_t)(it * 32 + vd_t) * NN + nk2 + voff_t);
        #pragma unroll
        for (int it = 0; it < 4; ++it)
            kreg[it] = *(const half8_t*)(Kb + (size_t)(nk2 + it * 16 + krow_t) * MID + koff_t);
        __builtin_amdgcn_sched_barrier(0);   // pin the loads above this point

        // ---- S^T strips from KBcur (staged last iter) ----
        floatx16 s0, s1;
        #pragma unroll
        for (int j = 0; j < 16; ++j) { s0[j] = 0.f; s1[j] = 0.f; }
        const _Float16* krow0 = KBcur + l31 * 136 + l5 * 8;
        const _Float16* krow1 = KBcur + (32 + l31) * 136 + l5 * 8;
        __builtin_amdgcn_s_setprio(1);
        #pragma unroll
        for (int ds = 0; ds < 8; ++ds) {
            s0 = __builtin_amdgcn_mfma_f32_32x32x16_f16(
                     *(const half8_t*)(krow0 + ds * 16), qf[ds], s0, 0, 0, 0);
            s1 = __builtin_amdgcn_mfma_f32_32x32x16_f16(
                     *(const half8_t*)(krow1 + ds * 16), qf[ds], s1, 0, 0, 0);
        }
        __builtin_amdgcn_s_setprio(0);

        // ---- online softmax over 64 k' ----
        float tmax = fmaxf(s0[0], s1[0]);
        #pragma unroll
        for (int j = 1; j < 16; ++j) tmax = fmaxf(tmax, fmaxf(s0[j], s1[j]));
        tmax = fmaxf(tmax, __shfl_xor(tmax, 32));

        if (!__all(tmax <= m_run)) {
            const float m_new = fmaxf(m_run, tmax);
            const float alpha = exp2f(m_run - m_new);
            m_run = m_new;
            l_run *= alpha;
            #pragma unroll
            for (int dt = 0; dt < 4; ++dt)
                #pragma unroll
                for (int j = 0; j < 16; ++j) o[dt][j] *= alpha;
        }

        float psum = 0.f;
        unsigned u0[8], u1[8];
        #pragma unroll
        for (int g = 0; g < 4; ++g) {
            float p0 = exp2f(s0[4 * g + 0] - m_run);
            float p1 = exp2f(s0[4 * g + 1] - m_run);
            float p2 = exp2f(s0[4 * g + 2] - m_run);
            float p3 = exp2f(s0[4 * g + 3] - m_run);
            psum += (p0 + p1) + (p2 + p3);
            u0[g] = pkrtz(p0, p1);
            u1[g] = pkrtz(p2, p3);
        }
        #pragma unroll
        for (int g = 0; g < 4; ++g) {
            float p0 = exp2f(s1[4 * g + 0] - m_run);
            float p1 = exp2f(s1[4 * g + 1] - m_run);
            float p2 = exp2f(s1[4 * g + 2] - m_run);
            float p3 = exp2f(s1[4 * g + 3] - m_run);
            psum += (p0 + p1) + (p2 + p3);
            u0[4 + g] = pkrtz(p0, p1);
            u1[4 + g] = pkrtz(p2, p3);
        }
        psum += __shfl_xor(psum, 32);
        l_run += psum;

        // ---- write K/V[kt+1] to the other buffers (nobody reads them now) ----
        #pragma unroll
        for (int it = 0; it < 4; ++it)
            *(half8_t*)(VBnxt + (it * 32 + vd_t) * 68 + voff_t) = vreg[it];
        #pragma unroll
        for (int it = 0; it < 4; ++it)
            *(half8_t*)(KBnxt + (it * 16 + krow_t) * 136 + koff_t) = kreg[it];

        // ---- O^T += V^T . P^T from VBcur (staged last iter) ----
        __builtin_amdgcn_s_setprio(1);
        #pragma unroll
        for (int ks = 0; ks < 4; ++ks) {
            i32x2 rA = __builtin_amdgcn_permlane32_swap(
                           (int)u0[2 * ks], (int)u0[2 * ks + 1], false, false);
            i32x2 rB = __builtin_amdgcn_permlane32_swap(
                           (int)u1[2 * ks], (int)u1[2 * ks + 1], false, false);
            u32x4 pw;
            pw[0] = (unsigned)rA[0]; pw[1] = (unsigned)rB[0];
            pw[2] = (unsigned)rA[1]; pw[3] = (unsigned)rB[1];
            half8_t pf = __builtin_bit_cast(half8_t, pw);
            const _Float16* vcol = VBcur + ks * 16 + l5 * 8;
            #pragma unroll
            for (int dt = 0; dt < 4; ++dt)
                o[dt] = __builtin_amdgcn_mfma_f32_32x32x16_f16(
                            *(const half8_t*)(vcol + (dt * 32 + l31) * 68), pf,
                            o[dt], 0, 0, 0);
        }
        __builtin_amdgcn_s_setprio(0);

        __syncthreads();   // ONE barrier: separates this iter's reads of cur
                           // from next iter's writes into cur.
    }

    // ---- per-row (m,l); transpose O via LDS; store UNNORMALIZED f16 ----
    if (l5 == 0) {
        float* mlb = MLg + ((size_t)(b * KS + sp) * 2) * NN;
        mlb[q0 + wave * 32 + l31]      = m_run;
        mlb[NN + q0 + wave * 32 + l31] = l_run;
    }

    #pragma unroll
    for (int dt = 0; dt < 4; ++dt)
        #pragma unroll
        for (int h = 0; h < 4; ++h) {
            half4_t v;
            #pragma unroll
            for (int i = 0; i < 4; ++i) v[i] = (_Float16)o[dt][4 * h + i];
            *(half4_t*)(Osh + (wave * 32 + l31) * 136 + dt * 32 + 8 * h + 4 * l5) = v;
        }
    __syncthreads();
    _Float16* Ob = Opart + ((size_t)(b * KS + sp) * NN + q0) * MID;
    #pragma unroll
    for (int it = 0; it < 8; ++it) {
        int c = it * 256 + t;
        int q = c >> 4, g = c & 15;
        *(half8_t*)(Ob + (size_t)q * MID + g * 8) =
            *(const half8_t*)(Osh + q * 136 + g * 8);
    }
}

// ---------------------------------------------------------------------------
// Combine the KS partials — UNCHANGED from R8.
// ---------------------------------------------------------------------------
__global__ __launch_bounds__(256, 4) void comb_kernel(
    const _Float16* __restrict__ Opart, const float* __restrict__ MLg,
    _Float16* __restrict__ attnW)
{
    const int t  = threadIdx.x;
    const int b  = blockIdx.y;
    const int q  = blockIdx.x * 32 + (t >> 3);
    const int dg = (t & 7) * 16;

    float mv[KS], lv[KS];
    float m_g = -3.0e38f;
    #pragma unroll
    for (int s = 0; s < KS; ++s) {
        const float* mlb = MLg + ((size_t)(b * KS + s) * 2) * NN;
        mv[s] = mlb[q];
        lv[s] = mlb[NN + q];
        m_g = fmaxf(m_g, mv[s]);
    }
    float lg = 0.f, w[KS];
    #pragma unroll
    for (int s = 0; s < KS; ++s) { w[s] = exp2f(mv[s] - m_g); lg += lv[s] * w[s]; }
    const float inv = 1.0f / lg;

    float acc[16];
    #pragma unroll
    for (int j = 0; j < 16; ++j) acc[j] = 0.f;
    #pragma unroll
    for (int s = 0; s < KS; ++s) {
        const half8_t* Op = (const half8_t*)(Opart + ((size_t)(b * KS + s) * NN + q) * MID + dg);
        half8_t v0 = Op[0], v1 = Op[1];
        #pragma unroll
        for (int j = 0; j < 8; ++j) {
            acc[j]     += (float)v0[j] * w[s];
            acc[8 + j] += (float)v1[j] * w[s];
        }
    }
    half8_t h0, h1;
    #pragma unroll
    for (int j = 0; j < 8; ++j) {
        h0[j] = (_Float16)(acc[j] * inv);
        h1[j] = (_Float16)(acc[8 + j] * inv);
    }
    half8_t* Ow = (half8_t*)(attnW + ((size_t)b * NN + q) * MID + dg);
    Ow[0] = h0; Ow[1] = h1;
}

// ---------------------------------------------------------------------------
// Epilogue (f16 MFMA, no LDS) — UNCHANGED from R8.
// ---------------------------------------------------------------------------
__global__ __launch_bounds__(256, 2) void epi_kernel(
    const _Float16* __restrict__ attnW, const float* __restrict__ w4,
    const float* __restrict__ b4, const float* __restrict__ x,
    float* __restrict__ out)
{
    const int t    = threadIdx.x;
    const int lane = t & 63;
    const int wave = t >> 6;
    const int l31  = lane & 31;
    const int l5   = lane >> 5;
    const int n0   = blockIdx.x * 64;
    const int b    = blockIdx.y;

    #pragma unroll
    for (int i = 0; i < 4; ++i) {
        const int tau = wave * 4 + i;
        const int ct = tau >> 1, nt = tau & 1;
        floatx16 acc;
        #pragma unroll
        for (int j = 0; j < 16; ++j) acc[j] = 0.f;

        const float* wrow = w4 + (size_t)(ct * 32 + l31) * MID + l5 * 8;
        const _Float16* brow = attnW + ((size_t)b * NN + n0 + nt * 32 + l31) * MID + l5 * 8;
        #pragma unroll
        for (int ds = 0; ds < 8; ++ds) {
            half8_t wf = cvt8(wrow + ds * 16);
            half8_t bf = *(const half8_t*)(brow + ds * 16);
            acc = __builtin_amdgcn_mfma_f32_32x32x16_f16(wf, bf, acc, 0, 0, 0);
        }
        #pragma unroll
        for (int j = 0; j < 16; ++j) {
            int c = ct * 32 + (j & 3) + 8 * (j >> 2) + 4 * l5;
            size_t off = ((size_t)b * CC + c) * NN + n0 + nt * 32 + l31;
            out[off] = acc[j] + b4[c] + x[off];
        }
    }
}

extern "C" void kernel_launch(void* const* d_in, const int* in_sizes, int n_in,
                              void* d_out, int out_size, void* d_ws, size_t ws_size,
                              hipStream_t stream)
{
    const float* x  = (const float*)d_in[0];
    const float* w1 = (const float*)d_in[1];
    const float* b1 = (const float*)d_in[2];
    const float* w2 = (const float*)d_in[3];
    const float* b2 = (const float*)d_in[4];
    const float* w3 = (const float*)d_in[5];
    const float* b3 = (const float*)d_in[6];
    const float* w4 = (const float*)d_in[7];
    const float* b4 = (const float*)d_in[8];
    float* out = (float*)d_out;

    // ws: Qg f16 | Kg f16 | VtG f16 | attnW f16 | MLg f32 (13.25 MB total)
    // Opart f16 [B][KS][N][128] aliases d_out (KS=4: exactly out_size).
    _Float16* Qg    = (_Float16*)d_ws;
    _Float16* Kg    = Qg + (size_t)BB * NN * MID;
    _Float16* VtG   = Kg + (size_t)BB * NN * MID;
    _Float16* attnW = VtG + (size_t)BB * NN * MID;
    float* MLg      = (float*)(attnW + (size_t)BB * NN * MID);
    _Float16* Opart = (_Float16*)d_out;

    proj_kernel<<<dim3(NN / 64, BB), 256, 0, stream>>>(x, w1, b1, w2, b2, w3, b3, Qg, Kg, VtG);
    attn_kernel<<<dim3(NN / QB, KS, BB), 256, 0, stream>>>(Qg, Kg, VtG, Opart, MLg);
    comb_kernel<<<dim3(NN / 32, BB), 256, 0, stream>>>(Opart, MLg, attnW);
    epi_kernel<<<dim3(NN / 64, BB), 256, 0, stream>>>(attnW, w4, b4, x, out);
}

// Round 10
// 287.077 us; speedup vs baseline: 1.0119x; 1.0119x over previous
//
#include <hip/hip_runtime.h>

// NonLocalBlock: B=2, C=256, N=D*H*W=6272, mid=128.
// R10 = R9 + T15 two-stage pipeline in attn (softmax/PV lag one tile):
//  - per iter: prefetch K[t+1],V[t] -> regs; QK[t] (MFMA pipe) from KBcur;
//    softmax[t-1]+PV[t-1] (VALU+MFMA) from saved scores sp0/sp1 and VBcur
//    (V[t-1], staged last iter); write-late staging; ONE barrier.
//    QK[t] and softmax[t-1] are independent -> MFMA/VALU pipes overlap
//    WITHIN a wave (R6-R9 ran them serially; VALUBusy 21% vs MfmaUtil 11%
//    were additive, should become max-like).
//  - proj: staging vectorized (4x4 reg transpose, ds_write_b64 x16 instead
//    of 128 scalar u16 writes per thread).
//  - everything else identical to R9 (KS=4, in-reg P, K/V dbuf, setprio,
//    f16 Opart in d_out, comb, MFMA epi).
// ws: Qg f16 | Kg f16 | VtG f16 | attnW f16 | MLg f32 = 13.25 MB.

#define BB  2
#define CC  256
#define NN  6272
#define MID 128
#define KS  4
#define QB  128
#define NT  (NN / 64)
#define LOG2E 1.4426950408889634f

typedef _Float16 half2_t __attribute__((ext_vector_type(2)));
typedef _Float16 half4_t __attribute__((ext_vector_type(4)));
typedef _Float16 half8_t __attribute__((ext_vector_type(8)));
typedef float    floatx16 __attribute__((ext_vector_type(16)));
typedef int      i32x2 __attribute__((ext_vector_type(2)));
typedef unsigned u32x4 __attribute__((ext_vector_type(4)));

__device__ __forceinline__ unsigned pkrtz(float a, float b) {
    return __builtin_bit_cast(unsigned, __builtin_amdgcn_cvt_pkrtz(a, b));
}
__device__ __forceinline__ half8_t cvt8(const float* p) {
    float4 f0 = *(const float4*)p;
    float4 f1 = *(const float4*)(p + 4);
    u32x4 u;
    u[0] = pkrtz(f0.x, f0.y); u[1] = pkrtz(f0.z, f0.w);
    u[2] = pkrtz(f1.x, f1.y); u[3] = pkrtz(f1.z, f1.w);
    return __builtin_bit_cast(half8_t, u);
}

// ---------------------------------------------------------------------------
// Projection (f16 MFMA, split-x). Staging now does a 4x4 register transpose
// and writes half4 pairs (ds_write_b64) instead of scalar u16 (16x fewer ops).
// grid (NN/64, BB), block 256 (4 waves).
// ---------------------------------------------------------------------------
__global__ __launch_bounds__(256, 2) void proj_kernel(
    const float* __restrict__ x,
    const float* __restrict__ w1, const float* __restrict__ bi1,
    const float* __restrict__ w2, const float* __restrict__ bi2,
    const float* __restrict__ w3, const float* __restrict__ bi3,
    _Float16* __restrict__ Qg, _Float16* __restrict__ Kg, _Float16* __restrict__ VtG)
{
    const int t    = threadIdx.x;
    const int lane = t & 63;
    const int wave = t >> 6;
    const int l31  = lane & 31;
    const int l5   = lane >> 5;
    const int n0   = blockIdx.x * 64;
    const int b    = blockIdx.y;

    __shared__ _Float16 xhi[64 * 140];
    __shared__ _Float16 xlo[64 * 140];

    floatx16 acc[6];
    #pragma unroll
    for (int i = 0; i < 6; ++i)
        #pragma unroll
        for (int j = 0; j < 16; ++j) acc[i][j] = 0.f;

    for (int phase = 0; phase < 2; ++phase) {
        const int cb = phase * 128;
        if (phase) __syncthreads();
        // ---- stage x[cb..+128][n0..+64] transposed+split, 4x4 micro-tiles ----
        #pragma unroll
        for (int a = t; a < 512; a += 256) {
            int cg = a >> 4, ng = a & 15;
            int c  = cg * 4, n4 = ng * 4;
            const float* xb = x + ((size_t)b * CC + cb + c) * NN + n0 + n4;
            float4 v0 = *(const float4*)(xb);
            float4 v1 = *(const float4*)(xb + NN);
            float4 v2 = *(const float4*)(xb + 2 * (size_t)NN);
            float4 v3 = *(const float4*)(xb + 3 * (size_t)NN);
            const float* pv[4] = {&v0.x, &v1.x, &v2.x, &v3.x};
            #pragma unroll
            for (int nn = 0; nn < 4; ++nn) {
                half4_t h, l;
                #pragma unroll
                for (int ci = 0; ci < 4; ++ci) {
                    float f = pv[ci][nn];
                    _Float16 hh = (_Float16)f;
                    h[ci] = hh;
                    l[ci] = (_Float16)(f - (float)hh);
                }
                *(half4_t*)&xhi[(n4 + nn) * 140 + c] = h;
                *(half4_t*)&xlo[(n4 + nn) * 140 + c] = l;
            }
        }
        __syncthreads();

        #pragma unroll
        for (int i = 0; i < 6; ++i) {
            const int tau = wave * 6 + i;
            const int pj = tau >> 3, mt = (tau >> 1) & 3, nt = tau & 1;
            const float* w = (pj == 0) ? w1 : (pj == 1) ? w2 : w3;
            const float* wrow = w + (size_t)(mt * 32 + l31) * CC + cb + l5 * 8;
            const _Float16* xr_hi = xhi + (nt * 32 + l31) * 140 + l5 * 8;
            const _Float16* xr_lo = xlo + (nt * 32 + l31) * 140 + l5 * 8;
            #pragma unroll
            for (int ds = 0; ds < 8; ++ds) {
                half8_t wf = cvt8(wrow + ds * 16);
                half8_t ah = *(const half8_t*)(xr_hi + ds * 16);
                half8_t al = *(const half8_t*)(xr_lo + ds * 16);
                if (pj < 2) {
                    acc[i] = __builtin_amdgcn_mfma_f32_32x32x16_f16(ah, wf, acc[i], 0, 0, 0);
                    acc[i] = __builtin_amdgcn_mfma_f32_32x32x16_f16(al, wf, acc[i], 0, 0, 0);
                } else {
                    acc[i] = __builtin_amdgcn_mfma_f32_32x32x16_f16(wf, ah, acc[i], 0, 0, 0);
                    acc[i] = __builtin_amdgcn_mfma_f32_32x32x16_f16(wf, al, acc[i], 0, 0, 0);
                }
            }
        }
    }

    #pragma unroll
    for (int i = 0; i < 6; ++i) {
        const int tau = wave * 6 + i;
        const int pj = tau >> 3, mt = (tau >> 1) & 3, nt = tau & 1;
        if (pj < 2) {
            const float bm = ((pj == 0) ? bi1 : bi2)[mt * 32 + l31];
            const float sc = (pj == 0) ? LOG2E : 1.0f;
            _Float16* eo = ((pj == 0) ? Qg : Kg) + (size_t)b * NN * MID;
            #pragma unroll
            for (int j = 0; j < 16; ++j) {
                int n = n0 + nt * 32 + (j & 3) + 8 * (j >> 2) + 4 * l5;
                eo[(size_t)n * MID + mt * 32 + l31] = (_Float16)((acc[i][j] + bm) * sc);
            }
        } else {
            _Float16* eo = VtG + (size_t)b * MID * NN;
            #pragma unroll
            for (int j = 0; j < 16; ++j) {
                int m = mt * 32 + (j & 3) + 8 * (j >> 2) + 4 * l5;
                eo[(size_t)m * NN + n0 + nt * 32 + l31] = (_Float16)(acc[i][j] + bi3[m]);
            }
        }
    }
}

// ---------------------------------------------------------------------------
// Flash attention partial: q-split 4-wave, KS=4, in-reg P, K/V dbuf,
// T15 two-stage pipeline (softmax/PV one tile behind QK), one barrier/iter.
// grid (NN/QB, KS, BB), block 256 (4 waves).
// LDS (69632 B): Ks0 | Ks1 [64][136] | Vt0 | Vt1 [128][68].
// Osh [128][136] h aliases Ks0+Ks1 for the store transpose.
// ---------------------------------------------------------------------------
__global__ __launch_bounds__(256, 2) void attn_kernel(
    const _Float16* __restrict__ Qg, const _Float16* __restrict__ Kg,
    const _Float16* __restrict__ VtG, _Float16* __restrict__ Opart,
    float* __restrict__ MLg)
{
    const int t    = threadIdx.x;
    const int lane = t & 63;
    const int wave = t >> 6;        // q-strip owner (0..3)
    const int l31  = lane & 31;
    const int l5   = lane >> 5;
    const int q0   = blockIdx.x * QB;
    const int sp   = blockIdx.y;
    const int b    = blockIdx.z;
    const int kt0  = (NT * sp) / KS;
    const int kt1  = (NT * (sp + 1)) / KS;

    __shared__ __align__(16) char lds[69632];
    _Float16* Ks0 = (_Float16*)lds;               // 64*136 halfs
    _Float16* Ks1 = (_Float16*)(lds + 17408);
    _Float16* Vt0 = (_Float16*)(lds + 34816);     // 128*68 halfs
    _Float16* Vt1 = (_Float16*)(lds + 52224);
    _Float16* Osh = (_Float16*)lds;               // [128][136] alias (Ks0+Ks1)

    const _Float16* Qb = Qg + ((size_t)b * NN + q0 + wave * 32) * MID;
    const _Float16* Kb = Kg + (size_t)b * NN * MID;
    const _Float16* Vb = VtG + (size_t)b * MID * NN;

    half8_t qf[8];
    #pragma unroll
    for (int ds = 0; ds < 8; ++ds)
        qf[ds] = *(const half8_t*)(Qb + (size_t)l31 * MID + ds * 16 + l5 * 8);

    floatx16 o[4];
    #pragma unroll
    for (int dt = 0; dt < 4; ++dt)
        #pragma unroll
        for (int j = 0; j < 16; ++j) o[dt][j] = 0.f;
    float m_run = -3.0e38f, l_run = 0.f;   // m in log2 domain

    const int krow_t = t >> 4, koff_t = (t & 15) * 8;
    const int vd_t   = t >> 3, voff_t = (t & 7) * 8;

    // softmax + PV for a PREVIOUS tile (scores p0/p1, V already in VB).
    auto smpv = [&](const floatx16& p0, const floatx16& p1, const _Float16* VB) {
        float tmax = fmaxf(p0[0], p1[0]);
        #pragma unroll
        for (int j = 1; j < 16; ++j) tmax = fmaxf(tmax, fmaxf(p0[j], p1[j]));
        tmax = fmaxf(tmax, __shfl_xor(tmax, 32));

        if (!__all(tmax <= m_run)) {     // defer-max THR=0 (exact)
            const float m_new = fmaxf(m_run, tmax);
            const float alpha = exp2f(m_run - m_new);
            m_run = m_new;
            l_run *= alpha;
            #pragma unroll
            for (int dt = 0; dt < 4; ++dt)
                #pragma unroll
                for (int j = 0; j < 16; ++j) o[dt][j] *= alpha;
        }

        float psum = 0.f;
        unsigned u0[8], u1[8];
        #pragma unroll
        for (int g = 0; g < 4; ++g) {
            float e0 = exp2f(p0[4 * g + 0] - m_run);
            float e1 = exp2f(p0[4 * g + 1] - m_run);
            float e2 = exp2f(p0[4 * g + 2] - m_run);
            float e3 = exp2f(p0[4 * g + 3] - m_run);
            psum += (e0 + e1) + (e2 + e3);
            u0[g] = pkrtz(e0, e1);
            u1[g] = pkrtz(e2, e3);
        }
        #pragma unroll
        for (int g = 0; g < 4; ++g) {
            float e0 = exp2f(p1[4 * g + 0] - m_run);
            float e1 = exp2f(p1[4 * g + 1] - m_run);
            float e2 = exp2f(p1[4 * g + 2] - m_run);
            float e3 = exp2f(p1[4 * g + 3] - m_run);
            psum += (e0 + e1) + (e2 + e3);
            u0[4 + g] = pkrtz(e0, e1);
            u1[4 + g] = pkrtz(e2, e3);
        }
        psum += __shfl_xor(psum, 32);
        l_run += psum;

        __builtin_amdgcn_s_setprio(1);
        #pragma unroll
        for (int ks = 0; ks < 4; ++ks) {
            i32x2 rA = __builtin_amdgcn_permlane32_swap(
                           (int)u0[2 * ks], (int)u0[2 * ks + 1], false, false);
            i32x2 rB = __builtin_amdgcn_permlane32_swap(
                           (int)u1[2 * ks], (int)u1[2 * ks + 1], false, false);
            u32x4 pw;
            pw[0] = (unsigned)rA[0]; pw[1] = (unsigned)rB[0];
            pw[2] = (unsigned)rA[1]; pw[3] = (unsigned)rB[1];
            half8_t pf = __builtin_bit_cast(half8_t, pw);
            const _Float16* vcol = VB + ks * 16 + l5 * 8;
            #pragma unroll
            for (int dt = 0; dt < 4; ++dt)
                o[dt] = __builtin_amdgcn_mfma_f32_32x32x16_f16(
                            *(const half8_t*)(vcol + (dt * 32 + l31) * 68), pf,
                            o[dt], 0, 0, 0);
        }
        __builtin_amdgcn_s_setprio(0);
    };

    // ---- prologue: stage K[kt0] -> Ks0 ----
    #pragma unroll
    for (int it = 0; it < 4; ++it) {
        int r = it * 16 + krow_t;
        *(half8_t*)(Ks0 + r * 136 + koff_t) =
            *(const half8_t*)(Kb + (size_t)(kt0 * 64 + r) * MID + koff_t);
    }
    __syncthreads();

    floatx16 sp0, sp1;   // previous tile's scores (live across the barrier)
    for (int kt = kt0, cbuf = 0; kt < kt1; ++kt, cbuf ^= 1) {
        const int nk = kt * 64;
        _Float16* KBcur = cbuf ? Ks1 : Ks0;
        _Float16* KBnxt = cbuf ? Ks0 : Ks1;
        _Float16* VBcur = cbuf ? Vt1 : Vt0;   // holds V[kt-1]
        _Float16* VBnxt = cbuf ? Vt0 : Vt1;   // receives V[kt]

        // ---- issue K[kt+1] and V[kt] global loads -> regs (EARLY) ----
        const int nk2 = (kt + 1 < kt1) ? nk + 64 : nk;   // tail: harmless reload
        half8_t vreg[4], kreg[4];
        #pragma unroll
        for (int it = 0; it < 4; ++it)
            vreg[it] = *(const half8_t*)(Vb + (size_t)(it * 32 + vd_t) * NN + nk + voff_t);
        #pragma unroll
        for (int it = 0; it < 4; ++it)
            kreg[it] = *(const half8_t*)(Kb + (size_t)(nk2 + it * 16 + krow_t) * MID + koff_t);
        __builtin_amdgcn_sched_barrier(0);   // pin the loads above this point

        // ---- QK[kt] from KBcur (staged last iter) — MFMA pipe ----
        floatx16 s0, s1;
        #pragma unroll
        for (int j = 0; j < 16; ++j) { s0[j] = 0.f; s1[j] = 0.f; }
        const _Float16* krow0 = KBcur + l31 * 136 + l5 * 8;
        const _Float16* krow1 = KBcur + (32 + l31) * 136 + l5 * 8;
        __builtin_amdgcn_s_setprio(1);
        #pragma unroll
        for (int ds = 0; ds < 8; ++ds) {
            s0 = __builtin_amdgcn_mfma_f32_32x32x16_f16(
                     *(const half8_t*)(krow0 + ds * 16), qf[ds], s0, 0, 0, 0);
            s1 = __builtin_amdgcn_mfma_f32_32x32x16_f16(
                     *(const half8_t*)(krow1 + ds * 16), qf[ds], s1, 0, 0, 0);
        }
        __builtin_amdgcn_s_setprio(0);

        // ---- softmax + PV for tile kt-1 (VALU overlaps QK's MFMA) ----
        if (kt > kt0) smpv(sp0, sp1, VBcur);

        // ---- write-late staging: V[kt] -> VBnxt, K[kt+1] -> KBnxt ----
        #pragma unroll
        for (int it = 0; it < 4; ++it)
            *(half8_t*)(VBnxt + (it * 32 + vd_t) * 68 + voff_t) = vreg[it];
        #pragma unroll
        for (int it = 0; it < 4; ++it)
            *(half8_t*)(KBnxt + (it * 16 + krow_t) * 136 + koff_t) = kreg[it];

        sp0 = s0; sp1 = s1;
        __syncthreads();   // publishes K[kt+1]/V[kt]; guards buffer reuse
    }

    // ---- drain: softmax + PV for the last tile (V in VB[final cbuf]) ----
    {
        const int cbE = (kt1 - kt0) & 1;
        smpv(sp0, sp1, cbE ? Vt1 : Vt0);
    }

    // ---- per-row (m,l); transpose O via LDS; store UNNORMALIZED f16 ----
    if (l5 == 0) {
        float* mlb = MLg + ((size_t)(b * KS + sp) * 2) * NN;
        mlb[q0 + wave * 32 + l31]      = m_run;
        mlb[NN + q0 + wave * 32 + l31] = l_run;
    }
    __syncthreads();   // all waves done with PV reads before Osh overwrites Ks
    #pragma unroll
    for (int dt = 0; dt < 4; ++dt)
        #pragma unroll
        for (int h = 0; h < 4; ++h) {
            half4_t v;
            #pragma unroll
            for (int i = 0; i < 4; ++i) v[i] = (_Float16)o[dt][4 * h + i];
            *(half4_t*)(Osh + (wave * 32 + l31) * 136 + dt * 32 + 8 * h + 4 * l5) = v;
        }
    __syncthreads();
    _Float16* Ob = Opart + ((size_t)(b * KS + sp) * NN + q0) * MID;
    #pragma unroll
    for (int it = 0; it < 8; ++it) {
        int c = it * 256 + t;
        int q = c >> 4, g = c & 15;
        *(half8_t*)(Ob + (size_t)q * MID + g * 8) =
            *(const half8_t*)(Osh + q * 136 + g * 8);
    }
}

// ---------------------------------------------------------------------------
// Combine the KS partials — UNCHANGED.
// ---------------------------------------------------------------------------
__global__ __launch_bounds__(256, 4) void comb_kernel(
    const _Float16* __restrict__ Opart, const float* __restrict__ MLg,
    _Float16* __restrict__ attnW)
{
    const int t  = threadIdx.x;
    const int b  = blockIdx.y;
    const int q  = blockIdx.x * 32 + (t >> 3);
    const int dg = (t & 7) * 16;

    float mv[KS], lv[KS];
    float m_g = -3.0e38f;
    #pragma unroll
    for (int s = 0; s < KS; ++s) {
        const float* mlb = MLg + ((size_t)(b * KS + s) * 2) * NN;
        mv[s] = mlb[q];
        lv[s] = mlb[NN + q];
        m_g = fmaxf(m_g, mv[s]);
    }
    float lg = 0.f, w[KS];
    #pragma unroll
    for (int s = 0; s < KS; ++s) { w[s] = exp2f(mv[s] - m_g); lg += lv[s] * w[s]; }
    const float inv = 1.0f / lg;

    float acc[16];
    #pragma unroll
    for (int j = 0; j < 16; ++j) acc[j] = 0.f;
    #pragma unroll
    for (int s = 0; s < KS; ++s) {
        const half8_t* Op = (const half8_t*)(Opart + ((size_t)(b * KS + s) * NN + q) * MID + dg);
        half8_t v0 = Op[0], v1 = Op[1];
        #pragma unroll
        for (int j = 0; j < 8; ++j) {
            acc[j]     += (float)v0[j] * w[s];
            acc[8 + j] += (float)v1[j] * w[s];
        }
    }
    half8_t h0, h1;
    #pragma unroll
    for (int j = 0; j < 8; ++j) {
        h0[j] = (_Float16)(acc[j] * inv);
        h1[j] = (_Float16)(acc[8 + j] * inv);
    }
    half8_t* Ow = (half8_t*)(attnW + ((size_t)b * NN + q) * MID + dg);
    Ow[0] = h0; Ow[1] = h1;
}

// ---------------------------------------------------------------------------
// Epilogue (f16 MFMA, no LDS) — UNCHANGED.
// ---------------------------------------------------------------------------
__global__ __launch_bounds__(256, 2) void epi_kernel(
    const _Float16* __restrict__ attnW, const float* __restrict__ w4,
    const float* __restrict__ b4, const float* __restrict__ x,
    float* __restrict__ out)
{
    const int t    = threadIdx.x;
    const int lane = t & 63;
    const int wave = t >> 6;
    const int l31  = lane & 31;
    const int l5   = lane >> 5;
    const int n0   = blockIdx.x * 64;
    const int b    = blockIdx.y;

    #pragma unroll
    for (int i = 0; i < 4; ++i) {
        const int tau = wave * 4 + i;
        const int ct = tau >> 1, nt = tau & 1;
        floatx16 acc;
        #pragma unroll
        for (int j = 0; j < 16; ++j) acc[j] = 0.f;

        const float* wrow = w4 + (size_t)(ct * 32 + l31) * MID + l5 * 8;
        const _Float16* brow = attnW + ((size_t)b * NN + n0 + nt * 32 + l31) * MID + l5 * 8;
        #pragma unroll
        for (int ds = 0; ds < 8; ++ds) {
            half8_t wf = cvt8(wrow + ds * 16);
            half8_t bf = *(const half8_t*)(brow + ds * 16);
            acc = __builtin_amdgcn_mfma_f32_32x32x16_f16(wf, bf, acc, 0, 0, 0);
        }
        #pragma unroll
        for (int j = 0; j < 16; ++j) {
            int c = ct * 32 + (j & 3) + 8 * (j >> 2) + 4 * l5;
            size_t off = ((size_t)b * CC + c) * NN + n0 + nt * 32 + l31;
            out[off] = acc[j] + b4[c] + x[off];
        }
    }
}

extern "C" void kernel_launch(void* const* d_in, const int* in_sizes, int n_in,
                              void* d_out, int out_size, void* d_ws, size_t ws_size,
                              hipStream_t stream)
{
    const float* x  = (const float*)d_in[0];
    const float* w1 = (const float*)d_in[1];
    const float* b1 = (const float*)d_in[2];
    const float* w2 = (const float*)d_in[3];
    const float* b2 = (const float*)d_in[4];
    const float* w3 = (const float*)d_in[5];
    const float* b3 = (const float*)d_in[6];
    const float* w4 = (const float*)d_in[7];
    const float* b4 = (const float*)d_in[8];
    float* out = (float*)d_out;

    // ws: Qg f16 | Kg f16 | VtG f16 | attnW f16 | MLg f32 (13.25 MB total)
    // Opart f16 [B][KS][N][128] aliases d_out (KS=4: exactly out_size).
    _Float16* Qg    = (_Float16*)d_ws;
    _Float16* Kg    = Qg + (size_t)BB * NN * MID;
    _Float16* VtG   = Kg + (size_t)BB * NN * MID;
    _Float16* attnW = VtG + (size_t)BB * NN * MID;
    float* MLg      = (float*)(attnW + (size_t)BB * NN * MID);
    _Float16* Opart = (_Float16*)d_out;

    proj_kernel<<<dim3(NN / 64, BB), 256, 0, stream>>>(x, w1, b1, w2, b2, w3, b3, Qg, Kg, VtG);
    attn_kernel<<<dim3(NN / QB, KS, BB), 256, 0, stream>>>(Qg, Kg, VtG, Opart, MLg);
    comb_kernel<<<dim3(NN / 32, BB), 256, 0, stream>>>(Opart, MLg, attnW);
    epi_kernel<<<dim3(NN / 64, BB), 256, 0, stream>>>(attnW, w4, b4, x, out);
}

// Round 11
// 280.305 us; speedup vs baseline: 1.0363x; 1.0242x over previous
//
#include <hip/hip_runtime.h>

// NonLocalBlock: B=2, C=256, N=D*H*W=6272, mid=128.
// R11 = best-known parts + XCD-panel-affinity swizzle in attn:
//  - attn loop reverted to R9 (best measured: K/V dbuf, single barrier,
//    in-reg P, setprio; R10's T15 two-stage was -7us, dropped).
//  - NEW: 1D grid 392 = 49 q-blocks x 8 (b,sp) combos; dispatch id
//    n = q*8 + c so n%8 (the XCD round-robin) = c = (b,sp): each XCD
//    serves ONE 802KB K/V panel -> L2-resident (FETCH was 31.4MB vs
//    9.6MB compulsory = 3.3x overfetch; K/V L2 misses put ~450-900cy
//    latency on the prefetch path, longer than the compute phase).
//  - proj: R10 (MFMA split-x, vectorized 4x4-transpose staging).
//  - comb, epi: unchanged (MFMA epi).
// ws: Qg f16 | Kg f16 | VtG f16 | attnW f16 | MLg f32 = 13.25 MB.

#define BB  2
#define CC  256
#define NN  6272
#define MID 128
#define KS  4
#define QB  128
#define NT  (NN / 64)
#define LOG2E 1.4426950408889634f

typedef _Float16 half2_t __attribute__((ext_vector_type(2)));
typedef _Float16 half4_t __attribute__((ext_vector_type(4)));
typedef _Float16 half8_t __attribute__((ext_vector_type(8)));
typedef float    floatx16 __attribute__((ext_vector_type(16)));
typedef int      i32x2 __attribute__((ext_vector_type(2)));
typedef unsigned u32x4 __attribute__((ext_vector_type(4)));

__device__ __forceinline__ unsigned pkrtz(float a, float b) {
    return __builtin_bit_cast(unsigned, __builtin_amdgcn_cvt_pkrtz(a, b));
}
__device__ __forceinline__ half8_t cvt8(const float* p) {
    float4 f0 = *(const float4*)p;
    float4 f1 = *(const float4*)(p + 4);
    u32x4 u;
    u[0] = pkrtz(f0.x, f0.y); u[1] = pkrtz(f0.z, f0.w);
    u[2] = pkrtz(f1.x, f1.y); u[3] = pkrtz(f1.z, f1.w);
    return __builtin_bit_cast(half8_t, u);
}

// ---------------------------------------------------------------------------
// Projection (f16 MFMA, split-x, vectorized staging) — UNCHANGED from R10.
// grid (NN/64, BB), block 256 (4 waves).
// ---------------------------------------------------------------------------
__global__ __launch_bounds__(256, 2) void proj_kernel(
    const float* __restrict__ x,
    const float* __restrict__ w1, const float* __restrict__ bi1,
    const float* __restrict__ w2, const float* __restrict__ bi2,
    const float* __restrict__ w3, const float* __restrict__ bi3,
    _Float16* __restrict__ Qg, _Float16* __restrict__ Kg, _Float16* __restrict__ VtG)
{
    const int t    = threadIdx.x;
    const int lane = t & 63;
    const int wave = t >> 6;
    const int l31  = lane & 31;
    const int l5   = lane >> 5;
    const int n0   = blockIdx.x * 64;
    const int b    = blockIdx.y;

    __shared__ _Float16 xhi[64 * 140];
    __shared__ _Float16 xlo[64 * 140];

    floatx16 acc[6];
    #pragma unroll
    for (int i = 0; i < 6; ++i)
        #pragma unroll
        for (int j = 0; j < 16; ++j) acc[i][j] = 0.f;

    for (int phase = 0; phase < 2; ++phase) {
        const int cb = phase * 128;
        if (phase) __syncthreads();
        #pragma unroll
        for (int a = t; a < 512; a += 256) {
            int cg = a >> 4, ng = a & 15;
            int c  = cg * 4, n4 = ng * 4;
            const float* xb = x + ((size_t)b * CC + cb + c) * NN + n0 + n4;
            float4 v0 = *(const float4*)(xb);
            float4 v1 = *(const float4*)(xb + NN);
            float4 v2 = *(const float4*)(xb + 2 * (size_t)NN);
            float4 v3 = *(const float4*)(xb + 3 * (size_t)NN);
            const float* pv[4] = {&v0.x, &v1.x, &v2.x, &v3.x};
            #pragma unroll
            for (int nn = 0; nn < 4; ++nn) {
                half4_t h, l;
                #pragma unroll
                for (int ci = 0; ci < 4; ++ci) {
                    float f = pv[ci][nn];
                    _Float16 hh = (_Float16)f;
                    h[ci] = hh;
                    l[ci] = (_Float16)(f - (float)hh);
                }
                *(half4_t*)&xhi[(n4 + nn) * 140 + c] = h;
                *(half4_t*)&xlo[(n4 + nn) * 140 + c] = l;
            }
        }
        __syncthreads();

        #pragma unroll
        for (int i = 0; i < 6; ++i) {
            const int tau = wave * 6 + i;
            const int pj = tau >> 3, mt = (tau >> 1) & 3, nt = tau & 1;
            const float* w = (pj == 0) ? w1 : (pj == 1) ? w2 : w3;
            const float* wrow = w + (size_t)(mt * 32 + l31) * CC + cb + l5 * 8;
            const _Float16* xr_hi = xhi + (nt * 32 + l31) * 140 + l5 * 8;
            const _Float16* xr_lo = xlo + (nt * 32 + l31) * 140 + l5 * 8;
            #pragma unroll
            for (int ds = 0; ds < 8; ++ds) {
                half8_t wf = cvt8(wrow + ds * 16);
                half8_t ah = *(const half8_t*)(xr_hi + ds * 16);
                half8_t al = *(const half8_t*)(xr_lo + ds * 16);
                if (pj < 2) {
                    acc[i] = __builtin_amdgcn_mfma_f32_32x32x16_f16(ah, wf, acc[i], 0, 0, 0);
                    acc[i] = __builtin_amdgcn_mfma_f32_32x32x16_f16(al, wf, acc[i], 0, 0, 0);
                } else {
                    acc[i] = __builtin_amdgcn_mfma_f32_32x32x16_f16(wf, ah, acc[i], 0, 0, 0);
                    acc[i] = __builtin_amdgcn_mfma_f32_32x32x16_f16(wf, al, acc[i], 0, 0, 0);
                }
            }
        }
    }

    #pragma unroll
    for (int i = 0; i < 6; ++i) {
        const int tau = wave * 6 + i;
        const int pj = tau >> 3, mt = (tau >> 1) & 3, nt = tau & 1;
        if (pj < 2) {
            const float bm = ((pj == 0) ? bi1 : bi2)[mt * 32 + l31];
            const float sc = (pj == 0) ? LOG2E : 1.0f;
            _Float16* eo = ((pj == 0) ? Qg : Kg) + (size_t)b * NN * MID;
            #pragma unroll
            for (int j = 0; j < 16; ++j) {
                int n = n0 + nt * 32 + (j & 3) + 8 * (j >> 2) + 4 * l5;
                eo[(size_t)n * MID + mt * 32 + l31] = (_Float16)((acc[i][j] + bm) * sc);
            }
        } else {
            _Float16* eo = VtG + (size_t)b * MID * NN;
            #pragma unroll
            for (int j = 0; j < 16; ++j) {
                int m = mt * 32 + (j & 3) + 8 * (j >> 2) + 4 * l5;
                eo[(size_t)m * NN + n0 + nt * 32 + l31] = (_Float16)(acc[i][j] + bi3[m]);
            }
        }
    }
}

// ---------------------------------------------------------------------------
// Flash attention partial (R9 loop + XCD panel-affinity swizzle).
// grid: 1D, 392 blocks; id n: c = n%8 -> (b,sp) panel (= XCD via round-robin),
// q-block = n/8. Block 256 threads (4 waves), wave owns 32 q-rows.
// LDS (69632 B): Ks0 | Ks1 [64][136] | Vt0 | Vt1 [128][68].
// Osh [128][136] h aliases Ks0+Ks1 for the store transpose.
// ---------------------------------------------------------------------------
__global__ __launch_bounds__(256, 2) void attn_kernel(
    const _Float16* __restrict__ Qg, const _Float16* __restrict__ Kg,
    const _Float16* __restrict__ VtG, _Float16* __restrict__ Opart,
    float* __restrict__ MLg)
{
    const int t    = threadIdx.x;
    const int lane = t & 63;
    const int wave = t >> 6;        // q-strip owner (0..3)
    const int l31  = lane & 31;
    const int l5   = lane >> 5;
    const int c8   = blockIdx.x & 7;    // (b,sp) combo -> XCD
    const int b    = c8 >> 2;
    const int sp   = c8 & 3;
    const int q0   = (blockIdx.x >> 3) * QB;
    const int kt0  = (NT * sp) / KS;
    const int kt1  = (NT * (sp + 1)) / KS;

    __shared__ __align__(16) char lds[69632];
    _Float16* Ks0 = (_Float16*)lds;               // 64*136 halfs
    _Float16* Ks1 = (_Float16*)(lds + 17408);
    _Float16* Vt0 = (_Float16*)(lds + 34816);     // 128*68 halfs
    _Float16* Vt1 = (_Float16*)(lds + 52224);
    _Float16* Osh = (_Float16*)lds;               // [128][136] alias (Ks0+Ks1)

    const _Float16* Qb = Qg + ((size_t)b * NN + q0 + wave * 32) * MID;
    const _Float16* Kb = Kg + (size_t)b * NN * MID;
    const _Float16* Vb = VtG + (size_t)b * MID * NN;

    half8_t qf[8];
    #pragma unroll
    for (int ds = 0; ds < 8; ++ds)
        qf[ds] = *(const half8_t*)(Qb + (size_t)l31 * MID + ds * 16 + l5 * 8);

    floatx16 o[4];
    #pragma unroll
    for (int dt = 0; dt < 4; ++dt)
        #pragma unroll
        for (int j = 0; j < 16; ++j) o[dt][j] = 0.f;
    float m_run = -3.0e38f, l_run = 0.f;   // m in log2 domain

    const int krow_t = t >> 4, koff_t = (t & 15) * 8;
    const int vd_t   = t >> 3, voff_t = (t & 7) * 8;

    // ---- prologue: stage K[kt0] -> Ks0, V[kt0] -> Vt0 ----
    #pragma unroll
    for (int it = 0; it < 4; ++it) {
        int r = it * 16 + krow_t;
        *(half8_t*)(Ks0 + r * 136 + koff_t) =
            *(const half8_t*)(Kb + (size_t)(kt0 * 64 + r) * MID + koff_t);
    }
    #pragma unroll
    for (int it = 0; it < 4; ++it) {
        int d = it * 32 + vd_t;
        *(half8_t*)(Vt0 + d * 68 + voff_t) =
            *(const half8_t*)(Vb + (size_t)d * NN + kt0 * 64 + voff_t);
    }
    __syncthreads();

    for (int kt = kt0, cbuf = 0; kt < kt1; ++kt, cbuf ^= 1) {
        const int nk = kt * 64;
        _Float16* KBcur = cbuf ? Ks1 : Ks0;
        _Float16* KBnxt = cbuf ? Ks0 : Ks1;
        _Float16* VBcur = cbuf ? Vt1 : Vt0;
        _Float16* VBnxt = cbuf ? Vt0 : Vt1;

        // ---- issue K[kt+1], V[kt+1] global loads -> regs (EARLY) ----
        const int nk2 = (kt + 1 < kt1) ? nk + 64 : nk;   // tail: harmless reload
        half8_t vreg[4], kreg[4];
        #pragma unroll
        for (int it = 0; it < 4; ++it)
            vreg[it] = *(const half8_t*)(Vb + (size_t)(it * 32 + vd_t) * NN + nk2 + voff_t);
        #pragma unroll
        for (int it = 0; it < 4; ++it)
            kreg[it] = *(const half8_t*)(Kb + (size_t)(nk2 + it * 16 + krow_t) * MID + koff_t);
        __builtin_amdgcn_sched_barrier(0);   // pin the loads above this point

        // ---- S^T strips from KBcur (staged last iter) ----
        floatx16 s0, s1;
        #pragma unroll
        for (int j = 0; j < 16; ++j) { s0[j] = 0.f; s1[j] = 0.f; }
        const _Float16* krow0 = KBcur + l31 * 136 + l5 * 8;
        const _Float16* krow1 = KBcur + (32 + l31) * 136 + l5 * 8;
        __builtin_amdgcn_s_setprio(1);
        #pragma unroll
        for (int ds = 0; ds < 8; ++ds) {
            s0 = __builtin_amdgcn_mfma_f32_32x32x16_f16(
                     *(const half8_t*)(krow0 + ds * 16), qf[ds], s0, 0, 0, 0);
            s1 = __builtin_amdgcn_mfma_f32_32x32x16_f16(
                     *(const half8_t*)(krow1 + ds * 16), qf[ds], s1, 0, 0, 0);
        }
        __builtin_amdgcn_s_setprio(0);

        // ---- online softmax over 64 k' ----
        float tmax = fmaxf(s0[0], s1[0]);
        #pragma unroll
        for (int j = 1; j < 16; ++j) tmax = fmaxf(tmax, fmaxf(s0[j], s1[j]));
        tmax = fmaxf(tmax, __shfl_xor(tmax, 32));

        if (!__all(tmax <= m_run)) {     // defer-max THR=0 (exact)
            const float m_new = fmaxf(m_run, tmax);
            const float alpha = exp2f(m_run - m_new);
            m_run = m_new;
            l_run *= alpha;
            #pragma unroll
            for (int dt = 0; dt < 4; ++dt)
                #pragma unroll
                for (int j = 0; j < 16; ++j) o[dt][j] *= alpha;
        }

        float psum = 0.f;
        unsigned u0[8], u1[8];
        #pragma unroll
        for (int g = 0; g < 4; ++g) {
            float p0 = exp2f(s0[4 * g + 0] - m_run);
            float p1 = exp2f(s0[4 * g + 1] - m_run);
            float p2 = exp2f(s0[4 * g + 2] - m_run);
            float p3 = exp2f(s0[4 * g + 3] - m_run);
            psum += (p0 + p1) + (p2 + p3);
            u0[g] = pkrtz(p0, p1);
            u1[g] = pkrtz(p2, p3);
        }
        #pragma unroll
        for (int g = 0; g < 4; ++g) {
            float p0 = exp2f(s1[4 * g + 0] - m_run);
            float p1 = exp2f(s1[4 * g + 1] - m_run);
            float p2 = exp2f(s1[4 * g + 2] - m_run);
            float p3 = exp2f(s1[4 * g + 3] - m_run);
            psum += (p0 + p1) + (p2 + p3);
            u0[4 + g] = pkrtz(p0, p1);
            u1[4 + g] = pkrtz(p2, p3);
        }
        psum += __shfl_xor(psum, 32);
        l_run += psum;

        // ---- write K/V[kt+1] to the other buffers (nobody reads them now) ----
        #pragma unroll
        for (int it = 0; it < 4; ++it)
            *(half8_t*)(VBnxt + (it * 32 + vd_t) * 68 + voff_t) = vreg[it];
        #pragma unroll
        for (int it = 0; it < 4; ++it)
            *(half8_t*)(KBnxt + (it * 16 + krow_t) * 136 + koff_t) = kreg[it];

        // ---- O^T += V^T . P^T from VBcur (staged last iter) ----
        __builtin_amdgcn_s_setprio(1);
        #pragma unroll
        for (int ks = 0; ks < 4; ++ks) {
            i32x2 rA = __builtin_amdgcn_permlane32_swap(
                           (int)u0[2 * ks], (int)u0[2 * ks + 1], false, false);
            i32x2 rB = __builtin_amdgcn_permlane32_swap(
                           (int)u1[2 * ks], (int)u1[2 * ks + 1], false, false);
            u32x4 pw;
            pw[0] = (unsigned)rA[0]; pw[1] = (unsigned)rB[0];
            pw[2] = (unsigned)rA[1]; pw[3] = (unsigned)rB[1];
            half8_t pf = __builtin_bit_cast(half8_t, pw);
            const _Float16* vcol = VBcur + ks * 16 + l5 * 8;
            #pragma unroll
            for (int dt = 0; dt < 4; ++dt)
                o[dt] = __builtin_amdgcn_mfma_f32_32x32x16_f16(
                            *(const half8_t*)(vcol + (dt * 32 + l31) * 68), pf,
                            o[dt], 0, 0, 0);
        }
        __builtin_amdgcn_s_setprio(0);

        __syncthreads();   // ONE barrier: this iter's reads of cur vs next writes
    }

    // ---- per-row (m,l); transpose O via LDS; store UNNORMALIZED f16 ----
    if (l5 == 0) {
        float* mlb = MLg + ((size_t)(b * KS + sp) * 2) * NN;
        mlb[q0 + wave * 32 + l31]      = m_run;
        mlb[NN + q0 + wave * 32 + l31] = l_run;
    }

    #pragma unroll
    for (int dt = 0; dt < 4; ++dt)
        #pragma unroll
        for (int h = 0; h < 4; ++h) {
            half4_t v;
            #pragma unroll
            for (int i = 0; i < 4; ++i) v[i] = (_Float16)o[dt][4 * h + i];
            *(half4_t*)(Osh + (wave * 32 + l31) * 136 + dt * 32 + 8 * h + 4 * l5) = v;
        }
    __syncthreads();
    _Float16* Ob = Opart + ((size_t)(b * KS + sp) * NN + q0) * MID;
    #pragma unroll
    for (int it = 0; it < 8; ++it) {
        int c = it * 256 + t;
        int q = c >> 4, g = c & 15;
        *(half8_t*)(Ob + (size_t)q * MID + g * 8) =
            *(const half8_t*)(Osh + q * 136 + g * 8);
    }
}

// ---------------------------------------------------------------------------
// Combine the KS partials — UNCHANGED.
// ---------------------------------------------------------------------------
__global__ __launch_bounds__(256, 4) void comb_kernel(
    const _Float16* __restrict__ Opart, const float* __restrict__ MLg,
    _Float16* __restrict__ attnW)
{
    const int t  = threadIdx.x;
    const int b  = blockIdx.y;
    const int q  = blockIdx.x * 32 + (t >> 3);
    const int dg = (t & 7) * 16;

    float mv[KS], lv[KS];
    float m_g = -3.0e38f;
    #pragma unroll
    for (int s = 0; s < KS; ++s) {
        const float* mlb = MLg + ((size_t)(b * KS + s) * 2) * NN;
        mv[s] = mlb[q];
        lv[s] = mlb[NN + q];
        m_g = fmaxf(m_g, mv[s]);
    }
    float lg = 0.f, w[KS];
    #pragma unroll
    for (int s = 0; s < KS; ++s) { w[s] = exp2f(mv[s] - m_g); lg += lv[s] * w[s]; }
    const float inv = 1.0f / lg;

    float acc[16];
    #pragma unroll
    for (int j = 0; j < 16; ++j) acc[j] = 0.f;
    #pragma unroll
    for (int s = 0; s < KS; ++s) {
        const half8_t* Op = (const half8_t*)(Opart + ((size_t)(b * KS + s) * NN + q) * MID + dg);
        half8_t v0 = Op[0], v1 = Op[1];
        #pragma unroll
        for (int j = 0; j < 8; ++j) {
            acc[j]     += (float)v0[j] * w[s];
            acc[8 + j] += (float)v1[j] * w[s];
        }
    }
    half8_t h0, h1;
    #pragma unroll
    for (int j = 0; j < 8; ++j) {
        h0[j] = (_Float16)(acc[j] * inv);
        h1[j] = (_Float16)(acc[8 + j] * inv);
    }
    half8_t* Ow = (half8_t*)(attnW + ((size_t)b * NN + q) * MID + dg);
    Ow[0] = h0; Ow[1] = h1;
}

// ---------------------------------------------------------------------------
// Epilogue (f16 MFMA, no LDS) — UNCHANGED.
// ---------------------------------------------------------------------------
__global__ __launch_bounds__(256, 2) void epi_kernel(
    const _Float16* __restrict__ attnW, const float* __restrict__ w4,
    const float* __restrict__ b4, const float* __restrict__ x,
    float* __restrict__ out)
{
    const int t    = threadIdx.x;
    const int lane = t & 63;
    const int wave = t >> 6;
    const int l31  = lane & 31;
    const int l5   = lane >> 5;
    const int n0   = blockIdx.x * 64;
    const int b    = blockIdx.y;

    #pragma unroll
    for (int i = 0; i < 4; ++i) {
        const int tau = wave * 4 + i;
        const int ct = tau >> 1, nt = tau & 1;
        floatx16 acc;
        #pragma unroll
        for (int j = 0; j < 16; ++j) acc[j] = 0.f;

        const float* wrow = w4 + (size_t)(ct * 32 + l31) * MID + l5 * 8;
        const _Float16* brow = attnW + ((size_t)b * NN + n0 + nt * 32 + l31) * MID + l5 * 8;
        #pragma unroll
        for (int ds = 0; ds < 8; ++ds) {
            half8_t wf = cvt8(wrow + ds * 16);
            half8_t bf = *(const half8_t*)(brow + ds * 16);
            acc = __builtin_amdgcn_mfma_f32_32x32x16_f16(wf, bf, acc, 0, 0, 0);
        }
        #pragma unroll
        for (int j = 0; j < 16; ++j) {
            int c = ct * 32 + (j & 3) + 8 * (j >> 2) + 4 * l5;
            size_t off = ((size_t)b * CC + c) * NN + n0 + nt * 32 + l31;
            out[off] = acc[j] + b4[c] + x[off];
        }
    }
}

extern "C" void kernel_launch(void* const* d_in, const int* in_sizes, int n_in,
                              void* d_out, int out_size, void* d_ws, size_t ws_size,
                              hipStream_t stream)
{
    const float* x  = (const float*)d_in[0];
    const float* w1 = (const float*)d_in[1];
    const float* b1 = (const float*)d_in[2];
    const float* w2 = (const float*)d_in[3];
    const float* b2 = (const float*)d_in[4];
    const float* w3 = (const float*)d_in[5];
    const float* b3 = (const float*)d_in[6];
    const float* w4 = (const float*)d_in[7];
    const float* b4 = (const float*)d_in[8];
    float* out = (float*)d_out;

    // ws: Qg f16 | Kg f16 | VtG f16 | attnW f16 | MLg f32 (13.25 MB total)
    // Opart f16 [B][KS][N][128] aliases d_out (KS=4: exactly out_size).
    _Float16* Qg    = (_Float16*)d_ws;
    _Float16* Kg    = Qg + (size_t)BB * NN * MID;
    _Float16* VtG   = Kg + (size_t)BB * NN * MID;
    _Float16* attnW = VtG + (size_t)BB * NN * MID;
    float* MLg      = (float*)(attnW + (size_t)BB * NN * MID);
    _Float16* Opart = (_Float16*)d_out;

    proj_kernel<<<dim3(NN / 64, BB), 256, 0, stream>>>(x, w1, b1, w2, b2, w3, b3, Qg, Kg, VtG);
    // 1D grid: 49 q-blocks x 8 (b,sp); id = q*8 + c so c lands on XCD c.
    attn_kernel<<<dim3((NN / QB) * KS * BB), 256, 0, stream>>>(Qg, Kg, VtG, Opart, MLg);
    comb_kernel<<<dim3(NN / 32, BB), 256, 0, stream>>>(Opart, MLg, attnW);
    epi_kernel<<<dim3(NN / 64, BB), 256, 0, stream>>>(attnW, w4, b4, x, out);
}

// Round 12
// 258.830 us; speedup vs baseline: 1.1223x; 1.0830x over previous
//
#include <hip/hip_runtime.h>

// NonLocalBlock: B=2, C=256, N=D*H*W=6272, mid=128.
// R12 = R11 attn/comb (unchanged, incl. XCD panel swizzle) + occupancy rework
// of proj and epi (the 136.7us non-attn block; proj/epi ran 196 blocks on
// 256 CUs = 23% of CUs idle):
//  - proj: n-tile 32 -> 392 blocks (1.53/CU); single staging phase
//    (xhi/xlo [32][260] = 33KB, ONE barrier); wave owns 3 (pj,mt) tiles;
//    96 independent w float4 loads/lane. Same fragment maps as R11 (nt=0).
//  - epi: n-tile 32 -> 392 blocks; 8 attnW B-frags loaded ONCE per wave,
//    reused across its 2 c-tiles; 16 MFMA/wave.
//  - attn: R11 verbatim (R9 loop + XCD (b,sp)%8 affinity; FETCH 9.46MB
//    = compulsory; 143.5us is the intra-wave dep-chain floor).
// ws: Qg f16 | Kg f16 | VtG f16 | attnW f16 | MLg f32 = 13.25 MB.

#define BB  2
#define CC  256
#define NN  6272
#define MID 128
#define KS  4
#define QB  128
#define NT  (NN / 64)
#define LOG2E 1.4426950408889634f

typedef _Float16 half2_t __attribute__((ext_vector_type(2)));
typedef _Float16 half4_t __attribute__((ext_vector_type(4)));
typedef _Float16 half8_t __attribute__((ext_vector_type(8)));
typedef float    floatx16 __attribute__((ext_vector_type(16)));
typedef int      i32x2 __attribute__((ext_vector_type(2)));
typedef unsigned u32x4 __attribute__((ext_vector_type(4)));

__device__ __forceinline__ unsigned pkrtz(float a, float b) {
    return __builtin_bit_cast(unsigned, __builtin_amdgcn_cvt_pkrtz(a, b));
}
__device__ __forceinline__ half8_t cvt8(const float* p) {
    float4 f0 = *(const float4*)p;
    float4 f1 = *(const float4*)(p + 4);
    u32x4 u;
    u[0] = pkrtz(f0.x, f0.y); u[1] = pkrtz(f0.z, f0.w);
    u[2] = pkrtz(f1.x, f1.y); u[3] = pkrtz(f1.z, f1.w);
    return __builtin_bit_cast(half8_t, u);
}

// ---------------------------------------------------------------------------
// Projection (f16 MFMA, split-x, 32-n tiles): e_pj[n][m] = w_pj @ x + bias.
// grid (NN/32, BB) = 392 blocks, block 256 (4 waves).
// Block: 32 n x 128 m x 3 proj = 12 (pj,mt) tiles; wave owns 3 (tau=wave*3+i:
// pj=tau>>2, mt=tau&3). x staged TRANSPOSED+SPLIT once: xhi/xlo [32][260] f16
// (260-pad: stride 130 dw = 2 mod 32 banks -> 2-way = free). ONE barrier.
// Fragment maps (verified): A lane->row, B lane->col, D row=(j&3)+8*(j>>2)+4*l5.
// ---------------------------------------------------------------------------
__global__ __launch_bounds__(256, 2) void proj_kernel(
    const float* __restrict__ x,
    const float* __restrict__ w1, const float* __restrict__ bi1,
    const float* __restrict__ w2, const float* __restrict__ bi2,
    const float* __restrict__ w3, const float* __restrict__ bi3,
    _Float16* __restrict__ Qg, _Float16* __restrict__ Kg, _Float16* __restrict__ VtG)
{
    const int t    = threadIdx.x;
    const int lane = t & 63;
    const int wave = t >> 6;
    const int l31  = lane & 31;
    const int l5   = lane >> 5;
    const int n0   = blockIdx.x * 32;
    const int b    = blockIdx.y;

    __shared__ _Float16 xhi[32 * 260];   // [n][c], stride 260
    __shared__ _Float16 xlo[32 * 260];

    // ---- stage x[b][0..256][n0..n0+32] transposed + hi/lo split ----
    #pragma unroll
    for (int a = t; a < 512; a += 256) {
        int cg = a >> 3, ng = a & 7;     // 64 c-groups x 8 n-groups
        int c  = cg * 4, n4 = ng * 4;
        const float* xb = x + ((size_t)b * CC + c) * NN + n0 + n4;
        float4 v0 = *(const float4*)(xb);
        float4 v1 = *(const float4*)(xb + NN);
        float4 v2 = *(const float4*)(xb + 2 * (size_t)NN);
        float4 v3 = *(const float4*)(xb + 3 * (size_t)NN);
        const float* pv[4] = {&v0.x, &v1.x, &v2.x, &v3.x};
        #pragma unroll
        for (int nn = 0; nn < 4; ++nn) {
            half4_t h, l;
            #pragma unroll
            for (int ci = 0; ci < 4; ++ci) {
                float f = pv[ci][nn];
                _Float16 hh = (_Float16)f;
                h[ci] = hh;
                l[ci] = (_Float16)(f - (float)hh);
            }
            *(half4_t*)&xhi[(n4 + nn) * 260 + c] = h;
            *(half4_t*)&xlo[(n4 + nn) * 260 + c] = l;
        }
    }
    __syncthreads();

    // ---- 3 tiles per wave, 16 k-steps each (full C=256), hi+lo MFMAs ----
    floatx16 acc[3];
    #pragma unroll
    for (int i = 0; i < 3; ++i)
        #pragma unroll
        for (int j = 0; j < 16; ++j) acc[i][j] = 0.f;

    #pragma unroll
    for (int i = 0; i < 3; ++i) {
        const int tau = wave * 3 + i;
        const int pj = tau >> 2, mt = tau & 3;
        const float* w = (pj == 0) ? w1 : (pj == 1) ? w2 : w3;
        const float* wrow = w + (size_t)(mt * 32 + l31) * CC + l5 * 8;
        const _Float16* xr_hi = xhi + l31 * 260 + l5 * 8;
        const _Float16* xr_lo = xlo + l31 * 260 + l5 * 8;
        #pragma unroll
        for (int ds = 0; ds < 16; ++ds) {
            half8_t wf = cvt8(wrow + ds * 16);
            half8_t ah = *(const half8_t*)(xr_hi + ds * 16);
            half8_t al = *(const half8_t*)(xr_lo + ds * 16);
            if (pj < 2) {   // D[n][m]: A = x (rows n), B = w (cols m)
                acc[i] = __builtin_amdgcn_mfma_f32_32x32x16_f16(ah, wf, acc[i], 0, 0, 0);
                acc[i] = __builtin_amdgcn_mfma_f32_32x32x16_f16(al, wf, acc[i], 0, 0, 0);
            } else {        // D[m][n]: A = w (rows m), B = x (cols n)
                acc[i] = __builtin_amdgcn_mfma_f32_32x32x16_f16(wf, ah, acc[i], 0, 0, 0);
                acc[i] = __builtin_amdgcn_mfma_f32_32x32x16_f16(wf, al, acc[i], 0, 0, 0);
            }
        }
    }

    // ---- stores ----
    #pragma unroll
    for (int i = 0; i < 3; ++i) {
        const int tau = wave * 3 + i;
        const int pj = tau >> 2, mt = tau & 3;
        if (pj < 2) {
            // D[n][m]: lane col m = mt*32+l31; rows n = n0 + rowof(j)
            const float bm = ((pj == 0) ? bi1 : bi2)[mt * 32 + l31];
            const float sc = (pj == 0) ? LOG2E : 1.0f;
            _Float16* eo = ((pj == 0) ? Qg : Kg) + (size_t)b * NN * MID;
            #pragma unroll
            for (int j = 0; j < 16; ++j) {
                int n = n0 + (j & 3) + 8 * (j >> 2) + 4 * l5;
                eo[(size_t)n * MID + mt * 32 + l31] = (_Float16)((acc[i][j] + bm) * sc);
            }
        } else {
            // D[m][n]: lane col n = n0+l31; rows m = mt*32 + rowof(j)
            _Float16* eo = VtG + (size_t)b * MID * NN;
            #pragma unroll
            for (int j = 0; j < 16; ++j) {
                int m = mt * 32 + (j & 3) + 8 * (j >> 2) + 4 * l5;
                eo[(size_t)m * NN + n0 + l31] = (_Float16)(acc[i][j] + bi3[m]);
            }
        }
    }
}

// ---------------------------------------------------------------------------
// Flash attention partial — UNCHANGED R11 (R9 loop + XCD panel swizzle).
// grid: 1D 392; id n: c8 = n%8 -> (b,sp) panel (= XCD), q-block = n/8.
// LDS (69632 B): Ks0 | Ks1 [64][136] | Vt0 | Vt1 [128][68].
// ---------------------------------------------------------------------------
__global__ __launch_bounds__(256, 2) void attn_kernel(
    const _Float16* __restrict__ Qg, const _Float16* __restrict__ Kg,
    const _Float16* __restrict__ VtG, _Float16* __restrict__ Opart,
    float* __restrict__ MLg)
{
    const int t    = threadIdx.x;
    const int lane = t & 63;
    const int wave = t >> 6;        // q-strip owner (0..3)
    const int l31  = lane & 31;
    const int l5   = lane >> 5;
    const int c8   = blockIdx.x & 7;    // (b,sp) combo -> XCD
    const int b    = c8 >> 2;
    const int sp   = c8 & 3;
    const int q0   = (blockIdx.x >> 3) * QB;
    const int kt0  = (NT * sp) / KS;
    const int kt1  = (NT * (sp + 1)) / KS;

    __shared__ __align__(16) char lds[69632];
    _Float16* Ks0 = (_Float16*)lds;               // 64*136 halfs
    _Float16* Ks1 = (_Float16*)(lds + 17408);
    _Float16* Vt0 = (_Float16*)(lds + 34816);     // 128*68 halfs
    _Float16* Vt1 = (_Float16*)(lds + 52224);
    _Float16* Osh = (_Float16*)lds;               // [128][136] alias (Ks0+Ks1)

    const _Float16* Qb = Qg + ((size_t)b * NN + q0 + wave * 32) * MID;
    const _Float16* Kb = Kg + (size_t)b * NN * MID;
    const _Float16* Vb = VtG + (size_t)b * MID * NN;

    half8_t qf[8];
    #pragma unroll
    for (int ds = 0; ds < 8; ++ds)
        qf[ds] = *(const half8_t*)(Qb + (size_t)l31 * MID + ds * 16 + l5 * 8);

    floatx16 o[4];
    #pragma unroll
    for (int dt = 0; dt < 4; ++dt)
        #pragma unroll
        for (int j = 0; j < 16; ++j) o[dt][j] = 0.f;
    float m_run = -3.0e38f, l_run = 0.f;   // m in log2 domain

    const int krow_t = t >> 4, koff_t = (t & 15) * 8;
    const int vd_t   = t >> 3, voff_t = (t & 7) * 8;

    // ---- prologue: stage K[kt0] -> Ks0, V[kt0] -> Vt0 ----
    #pragma unroll
    for (int it = 0; it < 4; ++it) {
        int r = it * 16 + krow_t;
        *(half8_t*)(Ks0 + r * 136 + koff_t) =
            *(const half8_t*)(Kb + (size_t)(kt0 * 64 + r) * MID + koff_t);
    }
    #pragma unroll
    for (int it = 0; it < 4; ++it) {
        int d = it * 32 + vd_t;
        *(half8_t*)(Vt0 + d * 68 + voff_t) =
            *(const half8_t*)(Vb + (size_t)d * NN + kt0 * 64 + voff_t);
    }
    __syncthreads();

    for (int kt = kt0, cbuf = 0; kt < kt1; ++kt, cbuf ^= 1) {
        const int nk = kt * 64;
        _Float16* KBcur = cbuf ? Ks1 : Ks0;
        _Float16* KBnxt = cbuf ? Ks0 : Ks1;
        _Float16* VBcur = cbuf ? Vt1 : Vt0;
        _Float16* VBnxt = cbuf ? Vt0 : Vt1;

        // ---- issue K[kt+1], V[kt+1] global loads -> regs (EARLY) ----
        const int nk2 = (kt + 1 < kt1) ? nk + 64 : nk;   // tail: harmless reload
        half8_t vreg[4], kreg[4];
        #pragma unroll
        for (int it = 0; it < 4; ++it)
            vreg[it] = *(const half8_t*)(Vb + (size_t)(it * 32 + vd_t) * NN + nk2 + voff_t);
        #pragma unroll
        for (int it = 0; it < 4; ++it)
            kreg[it] = *(const half8_t*)(Kb + (size_t)(nk2 + it * 16 + krow_t) * MID + koff_t);
        __builtin_amdgcn_sched_barrier(0);   // pin the loads above this point

        // ---- S^T strips from KBcur (staged last iter) ----
        floatx16 s0, s1;
        #pragma unroll
        for (int j = 0; j < 16; ++j) { s0[j] = 0.f; s1[j] = 0.f; }
        const _Float16* krow0 = KBcur + l31 * 136 + l5 * 8;
        const _Float16* krow1 = KBcur + (32 + l31) * 136 + l5 * 8;
        __builtin_amdgcn_s_setprio(1);
        #pragma unroll
        for (int ds = 0; ds < 8; ++ds) {
            s0 = __builtin_amdgcn_mfma_f32_32x32x16_f16(
                     *(const half8_t*)(krow0 + ds * 16), qf[ds], s0, 0, 0, 0);
            s1 = __builtin_amdgcn_mfma_f32_32x32x16_f16(
                     *(const half8_t*)(krow1 + ds * 16), qf[ds], s1, 0, 0, 0);
        }
        __builtin_amdgcn_s_setprio(0);

        // ---- online softmax over 64 k' ----
        float tmax = fmaxf(s0[0], s1[0]);
        #pragma unroll
        for (int j = 1; j < 16; ++j) tmax = fmaxf(tmax, fmaxf(s0[j], s1[j]));
        tmax = fmaxf(tmax, __shfl_xor(tmax, 32));

        if (!__all(tmax <= m_run)) {     // defer-max THR=0 (exact)
            const float m_new = fmaxf(m_run, tmax);
            const float alpha = exp2f(m_run - m_new);
            m_run = m_new;
            l_run *= alpha;
            #pragma unroll
            for (int dt = 0; dt < 4; ++dt)
                #pragma unroll
                for (int j = 0; j < 16; ++j) o[dt][j] *= alpha;
        }

        float psum = 0.f;
        unsigned u0[8], u1[8];
        #pragma unroll
        for (int g = 0; g < 4; ++g) {
            float p0 = exp2f(s0[4 * g + 0] - m_run);
            float p1 = exp2f(s0[4 * g + 1] - m_run);
            float p2 = exp2f(s0[4 * g + 2] - m_run);
            float p3 = exp2f(s0[4 * g + 3] - m_run);
            psum += (p0 + p1) + (p2 + p3);
            u0[g] = pkrtz(p0, p1);
            u1[g] = pkrtz(p2, p3);
        }
        #pragma unroll
        for (int g = 0; g < 4; ++g) {
            float p0 = exp2f(s1[4 * g + 0] - m_run);
            float p1 = exp2f(s1[4 * g + 1] - m_run);
            float p2 = exp2f(s1[4 * g + 2] - m_run);
            float p3 = exp2f(s1[4 * g + 3] - m_run);
            psum += (p0 + p1) + (p2 + p3);
            u0[4 + g] = pkrtz(p0, p1);
            u1[4 + g] = pkrtz(p2, p3);
        }
        psum += __shfl_xor(psum, 32);
        l_run += psum;

        // ---- write K/V[kt+1] to the other buffers (nobody reads them now) ----
        #pragma unroll
        for (int it = 0; it < 4; ++it)
            *(half8_t*)(VBnxt + (it * 32 + vd_t) * 68 + voff_t) = vreg[it];
        #pragma unroll
        for (int it = 0; it < 4; ++it)
            *(half8_t*)(KBnxt + (it * 16 + krow_t) * 136 + koff_t) = kreg[it];

        // ---- O^T += V^T . P^T from VBcur (staged last iter) ----
        __builtin_amdgcn_s_setprio(1);
        #pragma unroll
        for (int ks = 0; ks < 4; ++ks) {
            i32x2 rA = __builtin_amdgcn_permlane32_swap(
                           (int)u0[2 * ks], (int)u0[2 * ks + 1], false, false);
            i32x2 rB = __builtin_amdgcn_permlane32_swap(
                           (int)u1[2 * ks], (int)u1[2 * ks + 1], false, false);
            u32x4 pw;
            pw[0] = (unsigned)rA[0]; pw[1] = (unsigned)rB[0];
            pw[2] = (unsigned)rA[1]; pw[3] = (unsigned)rB[1];
            half8_t pf = __builtin_bit_cast(half8_t, pw);
            const _Float16* vcol = VBcur + ks * 16 + l5 * 8;
            #pragma unroll
            for (int dt = 0; dt < 4; ++dt)
                o[dt] = __builtin_amdgcn_mfma_f32_32x32x16_f16(
                            *(const half8_t*)(vcol + (dt * 32 + l31) * 68), pf,
                            o[dt], 0, 0, 0);
        }
        __builtin_amdgcn_s_setprio(0);

        __syncthreads();   // ONE barrier: this iter's reads of cur vs next writes
    }

    // ---- per-row (m,l); transpose O via LDS; store UNNORMALIZED f16 ----
    if (l5 == 0) {
        float* mlb = MLg + ((size_t)(b * KS + sp) * 2) * NN;
        mlb[q0 + wave * 32 + l31]      = m_run;
        mlb[NN + q0 + wave * 32 + l31] = l_run;
    }

    #pragma unroll
    for (int dt = 0; dt < 4; ++dt)
        #pragma unroll
        for (int h = 0; h < 4; ++h) {
            half4_t v;
            #pragma unroll
            for (int i = 0; i < 4; ++i) v[i] = (_Float16)o[dt][4 * h + i];
            *(half4_t*)(Osh + (wave * 32 + l31) * 136 + dt * 32 + 8 * h + 4 * l5) = v;
        }
    __syncthreads();
    _Float16* Ob = Opart + ((size_t)(b * KS + sp) * NN + q0) * MID;
    #pragma unroll
    for (int it = 0; it < 8; ++it) {
        int c = it * 256 + t;
        int q = c >> 4, g = c & 15;
        *(half8_t*)(Ob + (size_t)q * MID + g * 8) =
            *(const half8_t*)(Osh + q * 136 + g * 8);
    }
}

// ---------------------------------------------------------------------------
// Combine the KS partials — UNCHANGED.
// ---------------------------------------------------------------------------
__global__ __launch_bounds__(256, 4) void comb_kernel(
    const _Float16* __restrict__ Opart, const float* __restrict__ MLg,
    _Float16* __restrict__ attnW)
{
    const int t  = threadIdx.x;
    const int b  = blockIdx.y;
    const int q  = blockIdx.x * 32 + (t >> 3);
    const int dg = (t & 7) * 16;

    float mv[KS], lv[KS];
    float m_g = -3.0e38f;
    #pragma unroll
    for (int s = 0; s < KS; ++s) {
        const float* mlb = MLg + ((size_t)(b * KS + s) * 2) * NN;
        mv[s] = mlb[q];
        lv[s] = mlb[NN + q];
        m_g = fmaxf(m_g, mv[s]);
    }
    float lg = 0.f, w[KS];
    #pragma unroll
    for (int s = 0; s < KS; ++s) { w[s] = exp2f(mv[s] - m_g); lg += lv[s] * w[s]; }
    const float inv = 1.0f / lg;

    float acc[16];
    #pragma unroll
    for (int j = 0; j < 16; ++j) acc[j] = 0.f;
    #pragma unroll
    for (int s = 0; s < KS; ++s) {
        const half8_t* Op = (const half8_t*)(Opart + ((size_t)(b * KS + s) * NN + q) * MID + dg);
        half8_t v0 = Op[0], v1 = Op[1];
        #pragma unroll
        for (int j = 0; j < 8; ++j) {
            acc[j]     += (float)v0[j] * w[s];
            acc[8 + j] += (float)v1[j] * w[s];
        }
    }
    half8_t h0, h1;
    #pragma unroll
    for (int j = 0; j < 8; ++j) {
        h0[j] = (_Float16)(acc[j] * inv);
        h1[j] = (_Float16)(acc[8 + j] * inv);
    }
    half8_t* Ow = (half8_t*)(attnW + ((size_t)b * NN + q) * MID + dg);
    Ow[0] = h0; Ow[1] = h1;
}

// ---------------------------------------------------------------------------
// Epilogue (f16 MFMA, no LDS, 32-n tiles): out = x + w4 @ attn^T + b4.
// grid (NN/32, BB) = 392 blocks, block 256 (4 waves). Wave owns 2 c-tiles;
// the 8 attnW B-frags (rows n = n0+l31) are loaded ONCE and reused.
// ---------------------------------------------------------------------------
__global__ __launch_bounds__(256, 2) void epi_kernel(
    const _Float16* __restrict__ attnW, const float* __restrict__ w4,
    const float* __restrict__ b4, const float* __restrict__ x,
    float* __restrict__ out)
{
    const int t    = threadIdx.x;
    const int lane = t & 63;
    const int wave = t >> 6;
    const int l31  = lane & 31;
    const int l5   = lane >> 5;
    const int n0   = blockIdx.x * 32;
    const int b    = blockIdx.y;

    // B-frags: row n = n0 + l31, shared by both c-tiles of this wave.
    half8_t bf[8];
    const _Float16* brow = attnW + ((size_t)b * NN + n0 + l31) * MID + l5 * 8;
    #pragma unroll
    for (int ds = 0; ds < 8; ++ds)
        bf[ds] = *(const half8_t*)(brow + ds * 16);

    #pragma unroll
    for (int i = 0; i < 2; ++i) {
        const int ct = wave * 2 + i;
        floatx16 acc;
        #pragma unroll
        for (int j = 0; j < 16; ++j) acc[j] = 0.f;

        const float* wrow = w4 + (size_t)(ct * 32 + l31) * MID + l5 * 8;
        #pragma unroll
        for (int ds = 0; ds < 8; ++ds) {
            half8_t wf = cvt8(wrow + ds * 16);
            acc = __builtin_amdgcn_mfma_f32_32x32x16_f16(wf, bf[ds], acc, 0, 0, 0);
        }
        // D[c][n]: lane col n = n0+l31; rows c = ct*32 + rowof(j)
        #pragma unroll
        for (int j = 0; j < 16; ++j) {
            int c = ct * 32 + (j & 3) + 8 * (j >> 2) + 4 * l5;
            size_t off = ((size_t)b * CC + c) * NN + n0 + l31;
            out[off] = acc[j] + b4[c] + x[off];
        }
    }
}

extern "C" void kernel_launch(void* const* d_in, const int* in_sizes, int n_in,
                              void* d_out, int out_size, void* d_ws, size_t ws_size,
                              hipStream_t stream)
{
    const float* x  = (const float*)d_in[0];
    const float* w1 = (const float*)d_in[1];
    const float* b1 = (const float*)d_in[2];
    const float* w2 = (const float*)d_in[3];
    const float* b2 = (const float*)d_in[4];
    const float* w3 = (const float*)d_in[5];
    const float* b3 = (const float*)d_in[6];
    const float* w4 = (const float*)d_in[7];
    const float* b4 = (const float*)d_in[8];
    float* out = (float*)d_out;

    // ws: Qg f16 | Kg f16 | VtG f16 | attnW f16 | MLg f32 (13.25 MB total)
    // Opart f16 [B][KS][N][128] aliases d_out (KS=4: exactly out_size).
    _Float16* Qg    = (_Float16*)d_ws;
    _Float16* Kg    = Qg + (size_t)BB * NN * MID;
    _Float16* VtG   = Kg + (size_t)BB * NN * MID;
    _Float16* attnW = VtG + (size_t)BB * NN * MID;
    float* MLg      = (float*)(attnW + (size_t)BB * NN * MID);
    _Float16* Opart = (_Float16*)d_out;

    proj_kernel<<<dim3(NN / 32, BB), 256, 0, stream>>>(x, w1, b1, w2, b2, w3, b3, Qg, Kg, VtG);
    // 1D grid: 49 q-blocks x 8 (b,sp); id = q*8 + c so c lands on XCD c.
    attn_kernel<<<dim3((NN / QB) * KS * BB), 256, 0, stream>>>(Qg, Kg, VtG, Opart, MLg);
    comb_kernel<<<dim3(NN / 32, BB), 256, 0, stream>>>(Opart, MLg, attnW);
    epi_kernel<<<dim3(NN / 32, BB), 256, 0, stream>>>(attnW, w4, b4, x, out);
}